// Round 13
// baseline (185.237 us; speedup 1.0000x reference)
//
#include <hip/hip_runtime.h>
#include <hip/hip_bf16.h>
#include <stdint.h>

// Fused causal attention head, MI355X (gfx950). Round 16.
// attn v8: static split-K=8, 2048 blocks x 256 thr, ALL co-resident
// (8 blocks/CU x 4 waves = 32-wave cap). Critical block = 8 tiles (was 16).
// batch=u&3 keeps the XCD<->batch L2 pinning that v7's work-stealing broke
// (v7: 48.9us attn — L2 thrash + drained pipelines). Single-buffered K/V
// (16KB) overlaid on the [64][65] osc merge buffer -> ~17KB LDS/block so
// 8 blocks/CU fit; two barriers/tile, reg-prefetch of j+1 after barrier 1.
// Inner math byte-identical to v5 (the probed variant). Longest-m-first
// dispatch order. combine folds 8 splits. wprep/proj byte-identical to R12.

#define EMBED 384
#define HEAD  64
#define NB    4
#define NT    4096
#define NROWS (NB * NT) // 16384
#define NSPLIT 8

#define SCALE_Q 0.18033688011112042f // 0.125 * log2(e), folded into Q

typedef short bf16x8 __attribute__((ext_vector_type(8)));
typedef float f32x4  __attribute__((ext_vector_type(4)));
typedef float f32x16 __attribute__((ext_vector_type(16)));

__device__ __forceinline__ unsigned short bfround(float f) {
    union { float f; unsigned u; } v; v.f = f;
    return (unsigned short)((v.u + 0x8000u) >> 16);
}
__device__ __forceinline__ unsigned packbf(float lo, float hi) {
    union { float f; unsigned u; } a, b; a.f = lo; b.f = hi;
    return ((a.u + 0x8000u) >> 16) | ((b.u + 0x8000u) & 0xFFFF0000u);
}
__device__ __forceinline__ unsigned cvtpk(float lo, float hi) {
    unsigned r;
    asm("v_cvt_pk_bf16_f32 %0, %1, %2" : "=v"(r) : "v"(lo), "v"(hi));
    return r;
}
// permlane32_swap: a's upper-32-lane values <-> b's lower-32-lane values.
__device__ __forceinline__ void pl_swap32(unsigned& a, unsigned& b) {
    asm("v_permlane32_swap_b32 %0, %1" : "+v"(a), "+v"(b));
}

// ---------------------------------------------------------------------------
__global__ __launch_bounds__(256)
void wprep_kernel(const float* __restrict__ Wq,
                  const float* __restrict__ Wk,
                  const float* __restrict__ Wv,
                  unsigned short* __restrict__ Wt)
{
    int idx = blockIdx.x * 256 + threadIdx.x;
    int k = idx / 192;
    int n = idx - k * 192;
    int sel = n >> 6, nc = n & 63;
    const float* wp = (sel == 0) ? Wq : ((sel == 1) ? Wk : Wv);
    Wt[n * EMBED + k] = bfround(wp[(size_t)k * HEAD + nc]);
}

// ---------------------------------------------------------------------------
// proj v2 (unchanged from R8, measured 7.0 us ~ at HBM floor).
// ---------------------------------------------------------------------------
__global__ __launch_bounds__(512)
void proj_kernel(const float* __restrict__ x,
                 const unsigned short* __restrict__ Wt,
                 unsigned short* __restrict__ Qo,
                 unsigned short* __restrict__ Ko,
                 unsigned short* __restrict__ Vto)
{
    __shared__ __attribute__((aligned(16))) unsigned short ws[2][192][128]; // 96KB
    __shared__ __attribute__((aligned(16))) unsigned short xs[2][64][128];  // 32KB
    unsigned short (*vbuf)[72] = (unsigned short (*)[72])&xs[1][0][0];

    const int t    = threadIdx.x;   // 0..511
    const int lane = t & 63;
    const int w    = t >> 6;        // 0..7
    const int quad = lane >> 4;
    const int l16  = lane & 15;
    const int wr   = w & 3;         // row group (16 rows)
    const int wc   = w >> 2;        // col group (96 cols)
    const int r0   = blockIdx.x * 64;

    const int xr  = t >> 5, xc4 = t & 31;
    const int xch = xc4 >> 1, xsub = (xc4 & 1) * 4;
    const int wrw = t >> 4, wcc = t & 15;

    f32x4 acc[6];
#pragma unroll
    for (int i = 0; i < 6; ++i) acc[i] = (f32x4){0.f, 0.f, 0.f, 0.f};

    float4 xv[4];
    uint4  wv[6];
#pragma unroll
    for (int i = 0; i < 4; ++i)
        xv[i] = *(const float4*)(x + (size_t)(r0 + xr + 16 * i) * EMBED + xc4 * 4);
#pragma unroll
    for (int i = 0; i < 6; ++i)
        wv[i] = *(const uint4*)(Wt + (size_t)(wrw + 32 * i) * EMBED + wcc * 8);

    int cur = 0;
#pragma unroll
    for (int ph = 0; ph < 3; ++ph) {
#pragma unroll
        for (int i = 0; i < 4; ++i) {
            int row = xr + 16 * i;
            uint2 pw; pw.x = packbf(xv[i].x, xv[i].y); pw.y = packbf(xv[i].z, xv[i].w);
            *(uint2*)&xs[cur][row][((xch ^ (row & 15)) << 3) + xsub] = pw;
        }
#pragma unroll
        for (int i = 0; i < 6; ++i) {
            int row = wrw + 32 * i;
            *(uint4*)&ws[cur][row][(wcc ^ (row & 15)) << 3] = wv[i];
        }
        __syncthreads();

        if (ph < 2) {
            const int k0 = (ph + 1) * 128;
#pragma unroll
            for (int i = 0; i < 4; ++i)
                xv[i] = *(const float4*)(x + (size_t)(r0 + xr + 16 * i) * EMBED + k0 + xc4 * 4);
#pragma unroll
            for (int i = 0; i < 6; ++i)
                wv[i] = *(const uint4*)(Wt + (size_t)(wrw + 32 * i) * EMBED + k0 + wcc * 8);
        }

#pragma unroll
        for (int s = 0; s < 4; ++s) {
            bf16x8 a = *(const bf16x8*)&xs[cur][wr * 16 + l16][((s * 4 + quad) ^ l16) << 3];
#pragma unroll
            for (int ng = 0; ng < 6; ++ng) {
                bf16x8 b = *(const bf16x8*)&ws[cur][wc * 96 + ng * 16 + l16][((s * 4 + quad) ^ l16) << 3];
                acc[ng] = __builtin_amdgcn_mfma_f32_16x16x32_bf16(a, b, acc[ng], 0, 0, 0);
            }
        }
        cur ^= 1;
    }
    __syncthreads();

#pragma unroll
    for (int ng = 0; ng < 6; ++ng) {
        int cg = wc * 96 + ng * 16 + l16;
#pragma unroll
        for (int r = 0; r < 4; ++r) {
            int row = r0 + wr * 16 + quad * 4 + r;
            float vv = acc[ng][r];
            if (cg < 64) {
                Qo[(size_t)row * HEAD + cg] = bfround(vv * SCALE_Q);
            } else if (cg < 128) {
                Ko[(size_t)row * HEAD + (cg - 64)] = bfround(vv);
            } else {
                vbuf[cg - 128][wr * 16 + quad * 4 + r] = bfround(vv);
            }
        }
    }
    __syncthreads();
    {
        const int batch = r0 >> 12;
        const int s0 = r0 & (NT - 1);
        const int d = t >> 3, c = t & 7;
        *(uint4*)(Vto + ((size_t)(batch * HEAD + d)) * NT + s0 + c * 8) =
            *(const uint4*)&vbuf[d][c * 8];
    }
}

// ---------------------------------------------------------------------------
// attn v8: 2048 blocks x 256 thr, static split-8. u: batch=u&3 (XCD-pinned),
// sp=(u>>2)&7, m=63-(u>>5) (longest first). kt = sp+8j <= m; ntiles <= 8.
// Single-buffer K/V overlaid on osc[64][65]; per tile: write LDS -> barrier
// -> reg-prefetch(j+1) -> compute -> barrier. Inner math = v5 (probed).
// Blocks with ntiles==0 write zero partials (full static coverage).
// ---------------------------------------------------------------------------
__global__ __launch_bounds__(256, 8)
void attn_kernel(const unsigned short* __restrict__ Qi,
                 const unsigned short* __restrict__ Ki,
                 const unsigned short* __restrict__ Vti,
                 float* __restrict__ opart,
                 float* __restrict__ lpart)
{
    // osc[64][65] f32 (16.64KB) doubles as K tile (first 8KB) + V^T tile
    // (next 8KB) during the tile loop; reused as the merge buffer after.
    __shared__ __attribute__((aligned(16))) float osc[64][65];
    __shared__ float rsc[64];
    unsigned short (*Kt)[64] = (unsigned short (*)[64])&osc[0][0];
    unsigned short (*Vs)[64] = (unsigned short (*)[64])((unsigned short*)&osc[0][0] + 4096);

    const int t    = threadIdx.x;   // 0..255
    const int w    = t >> 6;        // 0..3
    const int lane = t & 63;
    const int l32  = lane & 31;
    const int hi   = lane >> 5;
    const int qg   = w >> 1;        // 32-q group
    const int sh   = w & 1;         // 32-s half

    const int u = blockIdx.x;
    const int batch = u & 3;        // XCD-pinned (u%8 placement -> fixed batch)
    const int sp = (u >> 2) & 7;    // split 0..7
    const int m  = 63 - (u >> 5);   // longest-first dispatch order
    const int ntiles = (m >= sp) ? (((m - sp) >> 3) + 1) : 0;
    const int q0w = m * 64 + qg * 32;

    const unsigned short* Kbg = Ki  + (size_t)batch * NT * HEAD;
    const unsigned short* Vbg = Vti + (size_t)batch * HEAD * NT;

    // Q B-frags: bq[dc] = Q[q0w + l32][dc*16 + hi*8 + j] (Q carries scale)
    bf16x8 bq[4];
#pragma unroll
    for (int dc = 0; dc < 4; ++dc)
        bq[dc] = *(const bf16x8*)(Qi + (size_t)(batch * NT + q0w + l32) * HEAD
                                  + dc * 16 + hi * 8);

    f32x16 o0, o1;
#pragma unroll
    for (int i = 0; i < 16; ++i) { o0[i] = 0.f; o1[i] = 0.f; }
    float rs = 0.f;

    // staging: 2 K chunks + 2 V chunks (16B) per thread = 16KB tile pair
    const int srow0 = t >> 3, sc = t & 7;  // rows 0..31
    const int srow1 = srow0 + 32;          // rows 32..63
    const int scc0 = sc ^ (srow0 & 7);
    const int scc1 = sc ^ (srow1 & 7);
    const int r7 = l32 & 7;                // frag-read swizzle key

    uint4 kr0, kr1, vr0, vr1;
    if (ntiles > 0) {
        kr0 = *(const uint4*)(Kbg + (size_t)(sp * 64 + srow0) * HEAD + sc * 8);
        kr1 = *(const uint4*)(Kbg + (size_t)(sp * 64 + srow1) * HEAD + sc * 8);
        vr0 = *(const uint4*)(Vbg + (size_t)srow0 * NT + sp * 64 + sc * 8);
        vr1 = *(const uint4*)(Vbg + (size_t)srow1 * NT + sp * 64 + sc * 8);
    }

    for (int j = 0; j < ntiles; ++j) {
        const int kt = sp + 8 * j;
        *(uint4*)&Kt[srow0][scc0 * 8] = kr0;
        *(uint4*)&Kt[srow1][scc1 * 8] = kr1;
        *(uint4*)&Vs[srow0][scc0 * 8] = vr0;
        *(uint4*)&Vs[srow1][scc1 * 8] = vr1;
        __syncthreads(); // tile visible

        if (j + 1 < ntiles) { // reg-prefetch next tile; overlaps compute
            const int ktn = kt + 8;
            kr0 = *(const uint4*)(Kbg + (size_t)(ktn * 64 + srow0) * HEAD + sc * 8);
            kr1 = *(const uint4*)(Kbg + (size_t)(ktn * 64 + srow1) * HEAD + sc * 8);
            vr0 = *(const uint4*)(Vbg + (size_t)srow0 * NT + ktn * 64 + sc * 8);
            vr1 = *(const uint4*)(Vbg + (size_t)srow1 * NT + ktn * 64 + sc * 8);
        }

        // ---- QK^T over this wave's 32s x 32q ----
        f32x16 z;
#pragma unroll
        for (int i = 0; i < 16; ++i) z[i] = 0.f;
        const unsigned short* kb = &Kt[sh * 32 + l32][0];
#pragma unroll
        for (int dc = 0; dc < 4; ++dc) {
            bf16x8 ak = *(const bf16x8*)&kb[(((dc << 1) | hi) ^ r7) << 3];
            z = __builtin_amdgcn_mfma_f32_32x32x16_bf16(ak, bq[dc], z, 0, 0, 0);
        }

        // ---- exp2 + causal mask + row-sum + pack ----
        const bool diag = (kt == m);
        const int qglob = q0w + l32;
        float pq[16];
#pragma unroll
        for (int r = 0; r < 16; ++r) {
            float pv = __builtin_amdgcn_exp2f(z[r]);
            if (diag) {
                int sg = kt * 64 + sh * 32 + (r & 3) + 8 * (r >> 2) + 4 * hi;
                pv = (sg > qglob) ? 0.f : pv;
            }
            pq[r] = pv;
        }
        rs += (((pq[0] + pq[1]) + (pq[2] + pq[3])) + ((pq[4] + pq[5]) + (pq[6] + pq[7])))
            + (((pq[8] + pq[9]) + (pq[10] + pq[11])) + ((pq[12] + pq[13]) + (pq[14] + pq[15])));

        unsigned x0 = cvtpk(pq[0], pq[1]),  x1 = cvtpk(pq[2], pq[3]);
        unsigned x2 = cvtpk(pq[4], pq[5]),  x3 = cvtpk(pq[6], pq[7]);
        unsigned x4 = cvtpk(pq[8], pq[9]),  x5 = cvtpk(pq[10], pq[11]);
        unsigned x6 = cvtpk(pq[12], pq[13]), x7 = cvtpk(pq[14], pq[15]);
        pl_swap32(x0, x2); pl_swap32(x1, x3);
        pl_swap32(x4, x6); pl_swap32(x5, x7);
        union { unsigned uu[4]; bf16x8 v; } b0, b1;
        b0.uu[0] = x0; b0.uu[1] = x1; b0.uu[2] = x2; b0.uu[3] = x3;
        b1.uu[0] = x4; b1.uu[1] = x5; b1.uu[2] = x6; b1.uu[3] = x7;

        // ---- PV over this s-half ----
        const unsigned short* vb0 = &Vs[l32][0];
        const unsigned short* vb1 = &Vs[32 + l32][0];
#pragma unroll
        for (int sk = 0; sk < 2; ++sk) {
            const int c = sh * 4 + sk * 2 + hi;
            bf16x8 av0 = *(const bf16x8*)&vb0[((c ^ r7) << 3)];
            bf16x8 av1 = *(const bf16x8*)&vb1[((c ^ r7) << 3)];
            const bf16x8 bp = sk ? b1.v : b0.v;
            o0 = __builtin_amdgcn_mfma_f32_32x32x16_bf16(av0, bp, o0, 0, 0, 0);
            o1 = __builtin_amdgcn_mfma_f32_32x32x16_bf16(av1, bp, o1, 0, 0, 0);
        }
        __syncthreads(); // reads done; buffer reusable next iter (or as osc)
    }

    // ---- end merge across s-halves (osc overlays the retired K/V) ----
    float rs2 = rs + __shfl_xor(rs, 32, 64); // s-half sum for q = q0w+l32
    if (sh == 1) {
#pragma unroll
        for (int r = 0; r < 16; ++r) {
            osc[(r & 3) + 8 * (r >> 2) + 4 * hi][qg * 32 + l32] = o0[r];
            osc[32 + (r & 3) + 8 * (r >> 2) + 4 * hi][qg * 32 + l32] = o1[r];
        }
        if (lane < 32) rsc[qg * 32 + l32] = rs2;
    }
    __syncthreads();
    if (sh == 0) {
#pragma unroll
        for (int r = 0; r < 16; ++r) {
            osc[(r & 3) + 8 * (r >> 2) + 4 * hi][qg * 32 + l32] += o0[r];
            osc[32 + (r & 3) + 8 * (r >> 2) + 4 * hi][qg * 32 + l32] += o1[r];
        }
        if (lane < 32) {
            float rtot = rs2 + rsc[qg * 32 + l32];
            lpart[(size_t)sp * NROWS + batch * NT + m * 64 + qg * 32 + l32] = rtot;
        }
    }
    __syncthreads();
    // cooperative coalesced opart write: lanes 0..15 cover one q-row (256B)
    {
        float* ob = opart + (size_t)sp * NROWS * HEAD
                  + (size_t)(batch * NT + m * 64) * HEAD;
        const int d0 = (t & 15) * 4;
#pragma unroll
        for (int i = 0; i < 4; ++i) {
            const int q = i * 16 + (t >> 4);
            f32x4 v;
            v[0] = osc[d0 + 0][q]; v[1] = osc[d0 + 1][q];
            v[2] = osc[d0 + 2][q]; v[3] = osc[d0 + 3][q];
            *(f32x4*)&ob[(size_t)q * HEAD + d0] = v;
        }
    }
}

// ---------------------------------------------------------------------------
// combine: out = sum_sp(o_sp) / sum_sp(l_sp) over 8 splits.
// ---------------------------------------------------------------------------
__global__ __launch_bounds__(256)
void combine_kernel(const float* __restrict__ opart,
                    const float* __restrict__ lpart,
                    float* __restrict__ out)
{
    int gid = blockIdx.x * 256 + threadIdx.x;   // 0 .. NROWS*16-1
    int row = gid >> 4;
    int d4  = (gid & 15) * 4;
    const size_t st = (size_t)NROWS * HEAD;
    const float* p0 = opart + (size_t)row * HEAD + d4;
    f32x4 res = (f32x4){0.f, 0.f, 0.f, 0.f};
    float den = 0.f;
#pragma unroll
    for (int s = 0; s < NSPLIT; ++s) {
        res += *(const f32x4*)(p0 + (size_t)s * st);
        den += lpart[(size_t)s * NROWS + row];
    }
    float inv = 1.0f / den;
    res[0] *= inv; res[1] *= inv; res[2] *= inv; res[3] *= inv;
    *(f32x4*)(out + (size_t)row * HEAD + d4) = res;
}

extern "C" void kernel_launch(void* const* d_in, const int* in_sizes, int n_in,
                              void* d_out, int out_size, void* d_ws, size_t ws_size,
                              hipStream_t stream)
{
    const float* x  = (const float*)d_in[0];
    const float* Wq = (const float*)d_in[1];
    const float* Wk = (const float*)d_in[2];
    const float* Wv = (const float*)d_in[3];
    float* out = (float*)d_out;

    // ws: Q | K | V^T (bf16, 2MB each) | W^T (144KB) | opart (32MB, 8 splits)
    //     | lpart (512KB)
    unsigned short* Qw  = (unsigned short*)d_ws;
    unsigned short* Kw  = Qw + (size_t)NROWS * HEAD;
    unsigned short* Vtw = Kw + (size_t)NROWS * HEAD;
    unsigned short* Wtw = Vtw + (size_t)NROWS * HEAD;
    float* opart = (float*)(Wtw + (size_t)192 * EMBED);
    float* lpart = opart + (size_t)NSPLIT * NROWS * HEAD;

    wprep_kernel<<<(192 * EMBED) / 256, 256, 0, stream>>>(Wq, Wk, Wv, Wtw);
    proj_kernel<<<256, 512, 0, stream>>>(x, Wtw, Qw, Kw, Vtw);
    attn_kernel<<<2048, 256, 0, stream>>>(Qw, Kw, Vtw, opart, lpart);
    combine_kernel<<<NROWS * 16 / 256, 256, 0, stream>>>(opart, lpart, out);
}

// Round 14
// 108.859 us; speedup vs baseline: 1.7016x; 1.7016x over previous
//
#include <hip/hip_runtime.h>
#include <hip/hip_bf16.h>
#include <stdint.h>

// Fused causal attention head, MI355X (gfx950). Round 17.
// attn v9 = R12's v5, byte-identical EXCEPT the u->(m,sp,batch) map.
// R16 (v8) post-mortem: 2048-block split-8 hit a 7x HBM write amplification
// (230MB vs 34MB logical) -> dead end. R13 evidence stands: occupancy 29%
// because co-resident blocks {4c..4c+3} share one m (contiguous-4 placement).
// New map varies m with the LOW bits: b=u&3, c=u>>2, mm=c>>2, batch=c&3,
// sp=b, m = (b<2) ? mm : 63-mm. Co-resident quad = {mm,mm,63-mm,63-mm}
// (sum 126, balanced) under contiguous-4; roughly balanced under stride-256.
// Bijective; diag tile exists for every m; empty blocks zero-fill as before.
// wprep/proj/combine byte-identical to R12 (proj 7.0us at floor).

#define EMBED 384
#define HEAD  64
#define NB    4
#define NT    4096
#define NROWS (NB * NT) // 16384
#define NSPLIT 4

#define SCALE_Q 0.18033688011112042f // 0.125 * log2(e), folded into Q

typedef short bf16x8 __attribute__((ext_vector_type(8)));
typedef float f32x4  __attribute__((ext_vector_type(4)));
typedef float f32x16 __attribute__((ext_vector_type(16)));

__device__ __forceinline__ unsigned short bfround(float f) {
    union { float f; unsigned u; } v; v.f = f;
    return (unsigned short)((v.u + 0x8000u) >> 16);
}
__device__ __forceinline__ unsigned packbf(float lo, float hi) {
    union { float f; unsigned u; } a, b; a.f = lo; b.f = hi;
    return ((a.u + 0x8000u) >> 16) | ((b.u + 0x8000u) & 0xFFFF0000u);
}
__device__ __forceinline__ unsigned cvtpk(float lo, float hi) {
    unsigned r;
    asm("v_cvt_pk_bf16_f32 %0, %1, %2" : "=v"(r) : "v"(lo), "v"(hi));
    return r;
}
// permlane32_swap: a's upper-32-lane values <-> b's lower-32-lane values.
__device__ __forceinline__ void pl_swap32(unsigned& a, unsigned& b) {
    asm("v_permlane32_swap_b32 %0, %1" : "+v"(a), "+v"(b));
}

// ---------------------------------------------------------------------------
__global__ __launch_bounds__(256)
void wprep_kernel(const float* __restrict__ Wq,
                  const float* __restrict__ Wk,
                  const float* __restrict__ Wv,
                  unsigned short* __restrict__ Wt)
{
    int idx = blockIdx.x * 256 + threadIdx.x;
    int k = idx / 192;
    int n = idx - k * 192;
    int sel = n >> 6, nc = n & 63;
    const float* wp = (sel == 0) ? Wq : ((sel == 1) ? Wk : Wv);
    Wt[n * EMBED + k] = bfround(wp[(size_t)k * HEAD + nc]);
}

// ---------------------------------------------------------------------------
// proj v2 (unchanged from R8, measured 7.0 us ~ at HBM floor).
// ---------------------------------------------------------------------------
__global__ __launch_bounds__(512)
void proj_kernel(const float* __restrict__ x,
                 const unsigned short* __restrict__ Wt,
                 unsigned short* __restrict__ Qo,
                 unsigned short* __restrict__ Ko,
                 unsigned short* __restrict__ Vto)
{
    __shared__ __attribute__((aligned(16))) unsigned short ws[2][192][128]; // 96KB
    __shared__ __attribute__((aligned(16))) unsigned short xs[2][64][128];  // 32KB
    unsigned short (*vbuf)[72] = (unsigned short (*)[72])&xs[1][0][0];

    const int t    = threadIdx.x;   // 0..511
    const int lane = t & 63;
    const int w    = t >> 6;        // 0..7
    const int quad = lane >> 4;
    const int l16  = lane & 15;
    const int wr   = w & 3;         // row group (16 rows)
    const int wc   = w >> 2;        // col group (96 cols)
    const int r0   = blockIdx.x * 64;

    const int xr  = t >> 5, xc4 = t & 31;
    const int xch = xc4 >> 1, xsub = (xc4 & 1) * 4;
    const int wrw = t >> 4, wcc = t & 15;

    f32x4 acc[6];
#pragma unroll
    for (int i = 0; i < 6; ++i) acc[i] = (f32x4){0.f, 0.f, 0.f, 0.f};

    float4 xv[4];
    uint4  wv[6];
#pragma unroll
    for (int i = 0; i < 4; ++i)
        xv[i] = *(const float4*)(x + (size_t)(r0 + xr + 16 * i) * EMBED + xc4 * 4);
#pragma unroll
    for (int i = 0; i < 6; ++i)
        wv[i] = *(const uint4*)(Wt + (size_t)(wrw + 32 * i) * EMBED + wcc * 8);

    int cur = 0;
#pragma unroll
    for (int ph = 0; ph < 3; ++ph) {
#pragma unroll
        for (int i = 0; i < 4; ++i) {
            int row = xr + 16 * i;
            uint2 pw; pw.x = packbf(xv[i].x, xv[i].y); pw.y = packbf(xv[i].z, xv[i].w);
            *(uint2*)&xs[cur][row][((xch ^ (row & 15)) << 3) + xsub] = pw;
        }
#pragma unroll
        for (int i = 0; i < 6; ++i) {
            int row = wrw + 32 * i;
            *(uint4*)&ws[cur][row][(wcc ^ (row & 15)) << 3] = wv[i];
        }
        __syncthreads();

        if (ph < 2) {
            const int k0 = (ph + 1) * 128;
#pragma unroll
            for (int i = 0; i < 4; ++i)
                xv[i] = *(const float4*)(x + (size_t)(r0 + xr + 16 * i) * EMBED + k0 + xc4 * 4);
#pragma unroll
            for (int i = 0; i < 6; ++i)
                wv[i] = *(const uint4*)(Wt + (size_t)(wrw + 32 * i) * EMBED + k0 + wcc * 8);
        }

#pragma unroll
        for (int s = 0; s < 4; ++s) {
            bf16x8 a = *(const bf16x8*)&xs[cur][wr * 16 + l16][((s * 4 + quad) ^ l16) << 3];
#pragma unroll
            for (int ng = 0; ng < 6; ++ng) {
                bf16x8 b = *(const bf16x8*)&ws[cur][wc * 96 + ng * 16 + l16][((s * 4 + quad) ^ l16) << 3];
                acc[ng] = __builtin_amdgcn_mfma_f32_16x16x32_bf16(a, b, acc[ng], 0, 0, 0);
            }
        }
        cur ^= 1;
    }
    __syncthreads();

#pragma unroll
    for (int ng = 0; ng < 6; ++ng) {
        int cg = wc * 96 + ng * 16 + l16;
#pragma unroll
        for (int r = 0; r < 4; ++r) {
            int row = r0 + wr * 16 + quad * 4 + r;
            float vv = acc[ng][r];
            if (cg < 64) {
                Qo[(size_t)row * HEAD + cg] = bfround(vv * SCALE_Q);
            } else if (cg < 128) {
                Ko[(size_t)row * HEAD + (cg - 64)] = bfround(vv);
            } else {
                vbuf[cg - 128][wr * 16 + quad * 4 + r] = bfround(vv);
            }
        }
    }
    __syncthreads();
    {
        const int batch = r0 >> 12;
        const int s0 = r0 & (NT - 1);
        const int d = t >> 3, c = t & 7;
        *(uint4*)(Vto + ((size_t)(batch * HEAD + d)) * NT + s0 + c * 8) =
            *(const uint4*)&vbuf[d][c * 8];
    }
}

// ---------------------------------------------------------------------------
// attn v9: 1024 blocks x 256 thr. NEW MAP (only change vs R12):
//   b = u&3, c = u>>2, mm = c>>2, batch = c&3, sp = b,
//   m = (b < 2) ? mm : 63 - mm.
// Bijective; contiguous-4 co-resident quad = {mm,mm,63-mm,63-mm} (balanced).
// kt = sp + 4j <= m. 4 waves: qg=w>>1 (32q), sh=w&1 (32s). 32x32x16 MFMAs,
// dbuf K/V, one barrier/tile, prefetch-after-barrier, cvt_pk + permlane
// P-transform, osc-overlay merge, coalesced opart write.
// ---------------------------------------------------------------------------
__global__ __launch_bounds__(256, 4)
void attn_kernel(const unsigned short* __restrict__ Qi,
                 const unsigned short* __restrict__ Ki,
                 const unsigned short* __restrict__ Vti,
                 float* __restrict__ opart,
                 float* __restrict__ lpart)
{
    // KV[buf][0] = K tile [64s][64d], KV[buf][1] = V^T tile [64d][64s]. 32KB.
    __shared__ __attribute__((aligned(16))) unsigned short KV[2][2][64][64];
    __shared__ float rsc[64];

    const int t    = threadIdx.x;   // 0..255
    const int w    = t >> 6;        // 0..3
    const int lane = t & 63;
    const int l32  = lane & 31;
    const int hi   = lane >> 5;
    const int qg   = w >> 1;        // 32-q group
    const int sh   = w & 1;         // 32-s half

    const int u = blockIdx.x;
    const int b = u & 3;
    const int c = u >> 2;
    const int mm = c >> 2;
    const int batch = c & 3;
    const int sp = b;
    const int m = (b < 2) ? mm : (63 - mm);
    const int ntiles = (m >= sp) ? (((m - sp) >> 2) + 1) : 0;
    const int q0w = m * 64 + qg * 32;

    const unsigned short* Kbg = Ki  + (size_t)batch * NT * HEAD;
    const unsigned short* Vbg = Vti + (size_t)batch * HEAD * NT;

    // Q B-frags: bq[dc] = Q[q0w + l32][dc*16 + hi*8 + j] (Q carries scale)
    bf16x8 bq[4];
#pragma unroll
    for (int dc = 0; dc < 4; ++dc)
        bq[dc] = *(const bf16x8*)(Qi + (size_t)(batch * NT + q0w + l32) * HEAD
                                  + dc * 16 + hi * 8);

    f32x16 o0, o1;
#pragma unroll
    for (int i = 0; i < 16; ++i) { o0[i] = 0.f; o1[i] = 0.f; }
    float rs = 0.f;

    // staging (v2-proven indices): 2 K chunks + 2 V chunks per thread
    const int srow0 = t >> 3, sc = t & 7;  // rows 0..31
    const int srow1 = srow0 + 32;          // rows 32..63
    const int scc0 = sc ^ (srow0 & 7);
    const int scc1 = sc ^ (srow1 & 7);
    const int r7 = l32 & 7;                // frag-read swizzle key

    uint4 kr0, kr1, vr0, vr1;
    if (ntiles > 0) {
        kr0 = *(const uint4*)(Kbg + (size_t)(sp * 64 + srow0) * HEAD + sc * 8);
        kr1 = *(const uint4*)(Kbg + (size_t)(sp * 64 + srow1) * HEAD + sc * 8);
        vr0 = *(const uint4*)(Vbg + (size_t)srow0 * NT + sp * 64 + sc * 8);
        vr1 = *(const uint4*)(Vbg + (size_t)srow1 * NT + sp * 64 + sc * 8);
    }

    int cur = 0;
    for (int j = 0; j < ntiles; ++j) {
        const int kt = sp + 4 * j;
        *(uint4*)&KV[cur][0][srow0][scc0 * 8] = kr0;
        *(uint4*)&KV[cur][0][srow1][scc1 * 8] = kr1;
        *(uint4*)&KV[cur][1][srow0][scc0 * 8] = vr0;
        *(uint4*)&KV[cur][1][srow1][scc1 * 8] = vr1;
        __syncthreads(); // tile visible; j-1 reads complete

        if (j + 1 < ntiles) {
            const int ktn = kt + 4;
            kr0 = *(const uint4*)(Kbg + (size_t)(ktn * 64 + srow0) * HEAD + sc * 8);
            kr1 = *(const uint4*)(Kbg + (size_t)(ktn * 64 + srow1) * HEAD + sc * 8);
            vr0 = *(const uint4*)(Vbg + (size_t)srow0 * NT + ktn * 64 + sc * 8);
            vr1 = *(const uint4*)(Vbg + (size_t)srow1 * NT + ktn * 64 + sc * 8);
        }

        // ---- QK^T over this wave's 32s x 32q ----
        f32x16 z;
#pragma unroll
        for (int i = 0; i < 16; ++i) z[i] = 0.f;
        const unsigned short* kb = &KV[cur][0][sh * 32 + l32][0];
#pragma unroll
        for (int dc = 0; dc < 4; ++dc) {
            bf16x8 ak = *(const bf16x8*)&kb[(((dc << 1) | hi) ^ r7) << 3];
            z = __builtin_amdgcn_mfma_f32_32x32x16_bf16(ak, bq[dc], z, 0, 0, 0);
        }

        // ---- exp2 + causal mask + row-sum + pack ----
        const bool diag = (kt == m);
        const int qglob = q0w + l32;
        float pq[16];
#pragma unroll
        for (int r = 0; r < 16; ++r) {
            float pv = __builtin_amdgcn_exp2f(z[r]);
            if (diag) {
                int sg = kt * 64 + sh * 32 + (r & 3) + 8 * (r >> 2) + 4 * hi;
                pv = (sg > qglob) ? 0.f : pv;
            }
            pq[r] = pv;
        }
        rs += (((pq[0] + pq[1]) + (pq[2] + pq[3])) + ((pq[4] + pq[5]) + (pq[6] + pq[7])))
            + (((pq[8] + pq[9]) + (pq[10] + pq[11])) + ((pq[12] + pq[13]) + (pq[14] + pq[15])));

        unsigned x0 = cvtpk(pq[0], pq[1]),  x1 = cvtpk(pq[2], pq[3]);
        unsigned x2 = cvtpk(pq[4], pq[5]),  x3 = cvtpk(pq[6], pq[7]);
        unsigned x4 = cvtpk(pq[8], pq[9]),  x5 = cvtpk(pq[10], pq[11]);
        unsigned x6 = cvtpk(pq[12], pq[13]), x7 = cvtpk(pq[14], pq[15]);
        pl_swap32(x0, x2); pl_swap32(x1, x3);
        pl_swap32(x4, x6); pl_swap32(x5, x7);
        union { unsigned uu[4]; bf16x8 v; } b0, b1;
        b0.uu[0] = x0; b0.uu[1] = x1; b0.uu[2] = x2; b0.uu[3] = x3;
        b1.uu[0] = x4; b1.uu[1] = x5; b1.uu[2] = x6; b1.uu[3] = x7;

        // ---- PV over this s-half ----
        const unsigned short* vb0 = &KV[cur][1][l32][0];
        const unsigned short* vb1 = &KV[cur][1][32 + l32][0];
#pragma unroll
        for (int sk = 0; sk < 2; ++sk) {
            const int cc = sh * 4 + sk * 2 + hi;
            bf16x8 av0 = *(const bf16x8*)&vb0[((cc ^ r7) << 3)];
            bf16x8 av1 = *(const bf16x8*)&vb1[((cc ^ r7) << 3)];
            const bf16x8 bp = sk ? b1.v : b0.v;
            o0 = __builtin_amdgcn_mfma_f32_32x32x16_bf16(av0, bp, o0, 0, 0, 0);
            o1 = __builtin_amdgcn_mfma_f32_32x32x16_bf16(av1, bp, o1, 0, 0, 0);
        }
        cur ^= 1;
    }

    // ---- end merge across s-halves ----
    float rs2 = rs + __shfl_xor(rs, 32, 64); // s-half sum for q = q0w+l32
    __syncthreads(); // retire KV; reuse as osc
    float (*osc)[65] = (float (*)[65])&KV[0][0][0][0]; // [64][65] f32 = 16.6KB
    if (sh == 1) {
#pragma unroll
        for (int r = 0; r < 16; ++r) {
            osc[(r & 3) + 8 * (r >> 2) + 4 * hi][qg * 32 + l32] = o0[r];
            osc[32 + (r & 3) + 8 * (r >> 2) + 4 * hi][qg * 32 + l32] = o1[r];
        }
        if (lane < 32) rsc[qg * 32 + l32] = rs2;
    }
    __syncthreads();
    if (sh == 0) {
#pragma unroll
        for (int r = 0; r < 16; ++r) {
            osc[(r & 3) + 8 * (r >> 2) + 4 * hi][qg * 32 + l32] += o0[r];
            osc[32 + (r & 3) + 8 * (r >> 2) + 4 * hi][qg * 32 + l32] += o1[r];
        }
        if (lane < 32) {
            float rtot = rs2 + rsc[qg * 32 + l32];
            lpart[(size_t)sp * NROWS + batch * NT + m * 64 + qg * 32 + l32] = rtot;
        }
    }
    __syncthreads();
    // cooperative coalesced opart write: lanes 0..15 cover one q-row (256B)
    {
        float* ob = opart + (size_t)sp * NROWS * HEAD
                  + (size_t)(batch * NT + m * 64) * HEAD;
        const int d0 = (t & 15) * 4;
#pragma unroll
        for (int i = 0; i < 4; ++i) {
            const int q = i * 16 + (t >> 4);
            f32x4 v;
            v[0] = osc[d0 + 0][q]; v[1] = osc[d0 + 1][q];
            v[2] = osc[d0 + 2][q]; v[3] = osc[d0 + 3][q];
            *(f32x4*)&ob[(size_t)q * HEAD + d0] = v;
        }
    }
}

// ---------------------------------------------------------------------------
// combine: out = sum_sp(o_sp) / sum_sp(l_sp), one float4 per thread.
// ---------------------------------------------------------------------------
__global__ __launch_bounds__(256)
void combine_kernel(const float* __restrict__ opart,
                    const float* __restrict__ lpart,
                    float* __restrict__ out)
{
    int gid = blockIdx.x * 256 + threadIdx.x;   // 0 .. NROWS*16-1
    int row = gid >> 4;
    int d4  = (gid & 15) * 4;
    const size_t st = (size_t)NROWS * HEAD;
    const float* p0 = opart + (size_t)row * HEAD + d4;
    f32x4 a = *(const f32x4*)(p0);
    f32x4 b = *(const f32x4*)(p0 + st);
    f32x4 c = *(const f32x4*)(p0 + 2 * st);
    f32x4 d = *(const f32x4*)(p0 + 3 * st);
    float inv = 1.0f / (lpart[row] + lpart[NROWS + row] +
                        lpart[2 * NROWS + row] + lpart[3 * NROWS + row]);
    f32x4 res = (a + b) + (c + d);
    res[0] *= inv; res[1] *= inv; res[2] *= inv; res[3] *= inv;
    *(f32x4*)(out + (size_t)row * HEAD + d4) = res;
}

extern "C" void kernel_launch(void* const* d_in, const int* in_sizes, int n_in,
                              void* d_out, int out_size, void* d_ws, size_t ws_size,
                              hipStream_t stream)
{
    const float* x  = (const float*)d_in[0];
    const float* Wq = (const float*)d_in[1];
    const float* Wk = (const float*)d_in[2];
    const float* Wv = (const float*)d_in[3];
    float* out = (float*)d_out;

    // ws: Q | K | V^T (bf16, 2MB each) | W^T (144KB) | opart (16MB) | lpart (256KB)
    unsigned short* Qw  = (unsigned short*)d_ws;
    unsigned short* Kw  = Qw + (size_t)NROWS * HEAD;
    unsigned short* Vtw = Kw + (size_t)NROWS * HEAD;
    unsigned short* Wtw = Vtw + (size_t)NROWS * HEAD;
    float* opart = (float*)(Wtw + (size_t)192 * EMBED);
    float* lpart = opart + (size_t)NSPLIT * NROWS * HEAD;

    wprep_kernel<<<(192 * EMBED) / 256, 256, 0, stream>>>(Wq, Wk, Wv, Wtw);
    proj_kernel<<<256, 512, 0, stream>>>(x, Wtw, Qw, Kw, Vtw);
    attn_kernel<<<1024, 256, 0, stream>>>(Qw, Kw, Vtw, opart, lpart);
    combine_kernel<<<NROWS * 16 / 256, 256, 0, stream>>>(opart, lpart, out);
}